// Round 5
// baseline (766.015 us; speedup 1.0000x reference)
//
#include <hip/hip_runtime.h>
#include <hip/hip_bf16.h>

// Problem constants
constexpr int kB  = 1024;
constexpr int kV  = 6890;
constexpr int kJ  = 24;
constexpr int kNB = 10;
constexpr int kP  = 207;   // 23*9
constexpr int kH  = 17;
constexpr int TB  = 8;     // batch tile in k_verts

// Output layout (flat concat, FP32 elements — reference outputs are float32)
constexpr size_t O_VERTS  = 0;
constexpr size_t O_JOINTS = (size_t)kB * kV * 3;              // 21166080
constexpr size_t O_ROT    = O_JOINTS + (size_t)kB * kJ * 3;   // 21239808
constexpr size_t O_JFV    = O_ROT + (size_t)kB * kJ * 9;      // 21460992

// Workspace layout (fp32 elements)
constexpr size_t WS_JS   = 0;                       // 792 floats
constexpr size_t WS_FLAG = 1000;                    // 1 int (which 165360-buf is lbs)
constexpr size_t WS_A    = 1024;                    // kB*288
constexpr size_t WS_PF   = WS_A + (size_t)kB * 288; // kB*207
constexpr size_t WS_ROOT = WS_PF + (size_t)kB * kP; // kB*3
constexpr size_t WS_JFV  = WS_ROOT + (size_t)kB * 3;// kB*51

// ---------------------------------------------------------------------------
// Classifier: amb0/amb1 are the two 165360-element inputs (J_regressor (24,V)
// or lbs_weights (V,24)). lbs_weights row 0 sums to exactly 1 over its first
// 24 entries; J_regressor's first 24 flat entries sum to ~24/6890.
// flag=1 => amb0 is lbs_weights.
// ---------------------------------------------------------------------------
__global__ void k_classify(const float* __restrict__ amb0, int* __restrict__ flag)
{
    if (blockIdx.x == 0 && threadIdx.x == 0) {
        float s = 0.f;
        for (int i = 0; i < kJ; i++) s += amb0[i];
        *flag = (fabsf(s - 1.0f) < 0.5f) ? 1 : 0;
    }
}

// ---------------------------------------------------------------------------
// Kernel 0: precompute js[(j*3+k)*11 + l]:
//   l in 0..9  : sum_v Jreg[j,v] * shapedirs[v,k,l]
//   l == 10    : sum_v Jreg[j,v] * v_template[v,k]
// ---------------------------------------------------------------------------
__global__ __launch_bounds__(256) void k_js(
    const float* __restrict__ amb0,
    const float* __restrict__ amb1,
    const int* __restrict__ flag,
    const float* __restrict__ sd,
    const float* __restrict__ vt,
    float* __restrict__ js)
{
    const float* Jreg = (*flag) ? amb1 : amb0;
    int j = blockIdx.x / 11;
    int l = blockIdx.x % 11;
    int t = threadIdx.x;
    float a0 = 0.f, a1 = 0.f, a2 = 0.f;
    for (int v = t; v < kV; v += 256) {
        float w = Jreg[j * kV + v];
        if (l < kNB) {
            a0 += w * sd[(v * 3 + 0) * kNB + l];
            a1 += w * sd[(v * 3 + 1) * kNB + l];
            a2 += w * sd[(v * 3 + 2) * kNB + l];
        } else {
            a0 += w * vt[v * 3 + 0];
            a1 += w * vt[v * 3 + 1];
            a2 += w * vt[v * 3 + 2];
        }
    }
    __shared__ float r0[256], r1[256], r2[256];
    r0[t] = a0; r1[t] = a1; r2[t] = a2;
    __syncthreads();
    for (int s = 128; s > 0; s >>= 1) {
        if (t < s) { r0[t] += r0[t + s]; r1[t] += r1[t + s]; r2[t] += r2[t + s]; }
        __syncthreads();
    }
    if (t == 0) {
        js[(j * 3 + 0) * 11 + l] = r0[0];
        js[(j * 3 + 1) * 11 + l] = r1[0];
        js[(j * 3 + 2) * 11 + l] = r2[0];
    }
}

// ---------------------------------------------------------------------------
// Kernel 1: per-batch rodrigues + FK chain + A matrices.
// Parallel form (validated bit-equivalent to the serial form in R1/R3 bisect).
// ---------------------------------------------------------------------------
__global__ __launch_bounds__(64) void k_pose(
    const float* __restrict__ pose,
    const float* __restrict__ betas,
    const float* __restrict__ gor,
    const float* __restrict__ js,
    float* __restrict__ wsA,
    float* __restrict__ wsPF,
    float* __restrict__ wsRoot,
    float* __restrict__ out)
{
    __shared__ float Rsh[kJ][9];
    __shared__ float Jr[kJ][3];
    __shared__ float G[kJ][12];   // [m*4+n], translation at n==3

    int b = blockIdx.x;
    int t = threadIdx.x;

    if (t < kJ) {
        float rx, ry, rz;
        if (t == 0) {
            rx = gor[b * 3 + 0]; ry = gor[b * 3 + 1]; rz = gor[b * 3 + 2];
        } else {
            int o = b * 69 + (t - 1) * 3;
            rx = pose[o]; ry = pose[o + 1]; rz = pose[o + 2];
        }
        // reference: angle = ||rvec + 1e-8|| (componentwise add), axis = rvec/angle
        float ex = rx + 1e-8f, ey = ry + 1e-8f, ez = rz + 1e-8f;
        float ang = sqrtf(ex * ex + ey * ey + ez * ez);
        float x = rx / ang, y = ry / ang, z = rz / ang;
        float s = sinf(ang), c = cosf(ang), oc = 1.0f - c;
        float r[9];
        r[0] = 1.0f - oc * (y * y + z * z);
        r[1] = -s * z + oc * (x * y);
        r[2] =  s * y + oc * (x * z);
        r[3] =  s * z + oc * (x * y);
        r[4] = 1.0f - oc * (x * x + z * z);
        r[5] = -s * x + oc * (y * z);
        r[6] = -s * y + oc * (x * z);
        r[7] =  s * x + oc * (y * z);
        r[8] = 1.0f - oc * (x * x + y * y);
        #pragma unroll
        for (int i = 0; i < 9; i++) Rsh[t][i] = r[i];
        float* ro = out + O_ROT + (size_t)b * (kJ * 9) + (size_t)t * 9;
        #pragma unroll
        for (int i = 0; i < 9; i++) ro[i] = r[i];
        if (t >= 1) {
            float* pf = wsPF + (size_t)b * kP + (size_t)(t - 1) * 9;
            #pragma unroll
            for (int i = 0; i < 9; i++)
                pf[i] = r[i] - ((i == 0 || i == 4 || i == 8) ? 1.0f : 0.0f);
        }
        // rest joint t: js(:,10) + JS @ betas
        float bt[kNB];
        #pragma unroll
        for (int l = 0; l < kNB; l++) bt[l] = betas[b * kNB + l];
        #pragma unroll
        for (int k = 0; k < 3; k++) {
            const float* row = js + (t * 3 + k) * 11;
            float acc = row[10];
            #pragma unroll
            for (int l = 0; l < kNB; l++) acc += bt[l] * row[l];
            Jr[t][k] = acc;
        }
    }
    __syncthreads();

    if (t == 0) {
        const int par[kJ] = {-1,0,0,0,1,2,3,4,5,6,7,8,9,9,9,12,13,14,16,17,18,19,20,21};
        #pragma unroll
        for (int m = 0; m < 3; m++) {
            #pragma unroll
            for (int n = 0; n < 3; n++) G[0][m * 4 + n] = Rsh[0][m * 3 + n];
            G[0][m * 4 + 3] = Jr[0][m];
        }
        for (int i = 1; i < kJ; i++) {
            int p = par[i];
            float rel[3];
            #pragma unroll
            for (int k = 0; k < 3; k++) rel[k] = Jr[i][k] - Jr[p][k];
            #pragma unroll
            for (int m = 0; m < 3; m++) {
                float g0 = G[p][m * 4 + 0], g1 = G[p][m * 4 + 1], g2 = G[p][m * 4 + 2];
                #pragma unroll
                for (int n = 0; n < 3; n++) {
                    G[i][m * 4 + n] = g0 * Rsh[i][0 * 3 + n]
                                    + g1 * Rsh[i][1 * 3 + n]
                                    + g2 * Rsh[i][2 * 3 + n];
                }
                G[i][m * 4 + 3] = g0 * rel[0] + g1 * rel[1] + g2 * rel[2]
                                + G[p][m * 4 + 3];
            }
        }
    }
    __syncthreads();

    if (t < kJ) {
        float* Aj = wsA + (size_t)b * 288 + (size_t)t * 12;
        float* jo = out + O_JOINTS + (size_t)b * (kJ * 3) + (size_t)t * 3;
        #pragma unroll
        for (int m = 0; m < 3; m++) {
            float g0 = G[t][m * 4 + 0], g1 = G[t][m * 4 + 1], g2 = G[t][m * 4 + 2];
            Aj[m * 4 + 0] = g0;
            Aj[m * 4 + 1] = g1;
            Aj[m * 4 + 2] = g2;
            Aj[m * 4 + 3] = G[t][m * 4 + 3]
                          - (g0 * Jr[t][0] + g1 * Jr[t][1] + g2 * Jr[t][2]);
            jo[m] = G[t][m * 4 + 3] - G[0][m * 4 + 3];
        }
        if (t == 0) {
            #pragma unroll
            for (int k = 0; k < 3; k++) wsRoot[b * 3 + k] = G[0][k * 4 + 3];
        }
    }
}

// ---------------------------------------------------------------------------
// Kernel 2: fused per-vertex kernel, batch-tiled by TB.
//   v_posed = v_template + shapedirs@betas + posedirs^T@pose_feature
//   Tv = sum_j W[v,j] * A[b,j]   (3x4)
//   verts = Tv_rot @ v_posed + Tv_t - root
// ---------------------------------------------------------------------------
__global__ __launch_bounds__(256) void k_verts(
    const float* __restrict__ vt,
    const float* __restrict__ sd,
    const float* __restrict__ pd,
    const float* __restrict__ amb0,
    const float* __restrict__ amb1,
    const int* __restrict__ flag,
    const float* __restrict__ betas,
    const float* __restrict__ wsA,
    const float* __restrict__ wsPF,
    const float* __restrict__ wsRoot,
    float* __restrict__ out)
{
    __shared__ float sPF[TB][kP];
    __shared__ float sA[TB][288];
    __shared__ float sBT[TB][kNB];
    __shared__ float sRoot[TB][3];

    const float* W = (*flag) ? amb0 : amb1;   // lbs_weights (V,24)

    int t = threadIdx.x;
    int b0 = blockIdx.y * TB;

    for (int i = t; i < TB * kP; i += 256)
        sPF[i / kP][i % kP] = wsPF[(size_t)(b0 + i / kP) * kP + (i % kP)];
    for (int i = t; i < TB * 288; i += 256)
        sA[i / 288][i % 288] = wsA[(size_t)(b0 + i / 288) * 288 + (i % 288)];
    if (t < TB * kNB)
        sBT[t / kNB][t % kNB] = betas[(size_t)(b0 + t / kNB) * kNB + (t % kNB)];
    if (t < TB * 3)
        sRoot[t / 3][t % 3] = wsRoot[(size_t)(b0 + t / 3) * 3 + (t % 3)];
    __syncthreads();

    int v = blockIdx.x * 256 + t;
    if (v >= kV) return;

    float vp[TB][3];
    {
        float t0 = vt[v * 3 + 0], t1 = vt[v * 3 + 1], t2 = vt[v * 3 + 2];
        #pragma unroll
        for (int tb = 0; tb < TB; tb++) { vp[tb][0] = t0; vp[tb][1] = t1; vp[tb][2] = t2; }
    }
    // shapedirs @ betas
    {
        const float* sdp = sd + (size_t)v * 30;
        #pragma unroll
        for (int l = 0; l < kNB; l++) {
            float s0 = sdp[0 * kNB + l];
            float s1 = sdp[1 * kNB + l];
            float s2 = sdp[2 * kNB + l];
            #pragma unroll
            for (int tb = 0; tb < TB; tb++) {
                float bl = sBT[tb][l];
                vp[tb][0] += bl * s0;
                vp[tb][1] += bl * s1;
                vp[tb][2] += bl * s2;
            }
        }
    }
    // pose corrective
    {
        const float* pdp = pd + (size_t)v * 3;
        #pragma unroll 1
        for (int p = 0; p < kP; p++) {
            const float* q = pdp + (size_t)p * (kV * 3);
            float q0 = q[0], q1 = q[1], q2 = q[2];
            #pragma unroll
            for (int tb = 0; tb < TB; tb++) {
                float c = sPF[tb][p];
                vp[tb][0] += c * q0;
                vp[tb][1] += c * q1;
                vp[tb][2] += c * q2;
            }
        }
    }
    // LBS + output
    float w[kJ];
    {
        const float* Wv = W + (size_t)v * kJ;
        #pragma unroll
        for (int j = 0; j < kJ; j++) w[j] = Wv[j];
    }
    #pragma unroll 1
    for (int tb = 0; tb < TB; tb++) {
        float Tv[12];
        #pragma unroll
        for (int i = 0; i < 12; i++) Tv[i] = 0.f;
        #pragma unroll
        for (int j = 0; j < kJ; j++) {
            float wj = w[j];
            #pragma unroll
            for (int i = 0; i < 12; i++) Tv[i] += wj * sA[tb][j * 12 + i];
        }
        float x = vp[tb][0], y = vp[tb][1], z = vp[tb][2];
        float o0 = Tv[0] * x + Tv[1] * y + Tv[2]  * z + Tv[3]  - sRoot[tb][0];
        float o1 = Tv[4] * x + Tv[5] * y + Tv[6]  * z + Tv[7]  - sRoot[tb][1];
        float o2 = Tv[8] * x + Tv[9] * y + Tv[10] * z + Tv[11] - sRoot[tb][2];
        float* op = out + O_VERTS + ((size_t)(b0 + tb) * kV + v) * 3;
        op[0] = o0;
        op[1] = o1;
        op[2] = o2;
    }
}

// ---------------------------------------------------------------------------
// Kernel 3: jfv[b,j,k] = sum_v Jh[j,v] * verts_out[b,v,k]  (one block per b)
// (verts_out is root-subtracted; jfv - jfv[:, :1] is shift-invariant since
//  regressor rows sum to 1, residual error << threshold)
// ---------------------------------------------------------------------------
__global__ __launch_bounds__(256) void k_jfv(
    const float* __restrict__ Jh,
    const float* __restrict__ vertsOut,
    float* __restrict__ wsJfv)
{
    int b = blockIdx.x;
    int t = threadIdx.x;
    int lane = t & 63;
    int wave = t >> 6;

    float acc[kH * 3];
    #pragma unroll
    for (int i = 0; i < kH * 3; i++) acc[i] = 0.f;

    for (int v = t; v < kV; v += 256) {
        const float* vpt = vertsOut + ((size_t)b * kV + v) * 3;
        float vx = vpt[0], vy = vpt[1], vz = vpt[2];
        #pragma unroll
        for (int j = 0; j < kH; j++) {
            float wj = Jh[(size_t)j * kV + v];
            acc[j * 3 + 0] += wj * vx;
            acc[j * 3 + 1] += wj * vy;
            acc[j * 3 + 2] += wj * vz;
        }
    }
    #pragma unroll
    for (int off = 32; off > 0; off >>= 1) {
        #pragma unroll
        for (int i = 0; i < kH * 3; i++)
            acc[i] += __shfl_down(acc[i], off, 64);
    }
    __shared__ float partial[4][kH * 3];
    if (lane == 0) {
        #pragma unroll
        for (int i = 0; i < kH * 3; i++) partial[wave][i] = acc[i];
    }
    __syncthreads();
    if (t < kH * 3) {
        float s = partial[0][t] + partial[1][t] + partial[2][t] + partial[3][t];
        wsJfv[(size_t)b * 51 + t] = s;
    }
}

// ---------------------------------------------------------------------------
// Kernel 4: out = jfv - jfv[:, :1]
// ---------------------------------------------------------------------------
__global__ __launch_bounds__(64) void k_jfv_out(
    const float* __restrict__ wsJfv,
    float* __restrict__ out)
{
    int b = blockIdx.x;
    int t = threadIdx.x;
    if (t < kH * 3) {
        int k = t % 3;
        float val = wsJfv[(size_t)b * 51 + t] - wsJfv[(size_t)b * 51 + k];
        out[O_JFV + (size_t)b * 51 + t] = val;
    }
}

extern "C" void kernel_launch(void* const* d_in, const int* in_sizes, int n_in,
                              void* d_out, int out_size, void* d_ws, size_t ws_size,
                              hipStream_t stream) {
    // Map inputs by flat element count (robust to any pointer ordering).
    const float *pose = nullptr, *betas = nullptr, *gor = nullptr, *vt = nullptr,
                *sd = nullptr, *pd = nullptr, *Jh = nullptr;
    const float *amb0 = nullptr, *amb1 = nullptr;
    for (int i = 0; i < n_in; i++) {
        const float* p = (const float*)d_in[i];
        switch (in_sizes[i]) {
            case 70656:   pose  = p; break;  // (1024, 69)
            case 10240:   betas = p; break;  // (1024, 10)
            case 3072:    gor   = p; break;  // (1024, 3)
            case 20670:   vt    = p; break;  // (6890, 3)
            case 206700:  sd    = p; break;  // (6890, 3, 10)
            case 4278690: pd    = p; break;  // (207, 20670)
            case 117130:  Jh    = p; break;  // (17, 6890)
            case 165360:  if (!amb0) amb0 = p; else amb1 = p; break; // Jreg or lbs
            default: break;
        }
    }

    float* ws = (float*)d_ws;
    float* js     = ws + WS_JS;
    int*   flag   = (int*)(ws + WS_FLAG);
    float* wsA    = ws + WS_A;
    float* wsPF   = ws + WS_PF;
    float* wsRoot = ws + WS_ROOT;
    float* wsJfv  = ws + WS_JFV;

    float* out = (float*)d_out;

    k_classify<<<dim3(1), dim3(64), 0, stream>>>(amb0, flag);
    k_js<<<dim3(kJ * 11), dim3(256), 0, stream>>>(amb0, amb1, flag, sd, vt, js);
    k_pose<<<dim3(kB), dim3(64), 0, stream>>>(pose, betas, gor, js, wsA, wsPF, wsRoot, out);
    k_verts<<<dim3((kV + 255) / 256, kB / TB), dim3(256), 0, stream>>>(
        vt, sd, pd, amb0, amb1, flag, betas, wsA, wsPF, wsRoot, out);
    k_jfv<<<dim3(kB), dim3(256), 0, stream>>>(Jh, out + O_VERTS, wsJfv);
    k_jfv_out<<<dim3(kB), dim3(64), 0, stream>>>(wsJfv, out);
}

// Round 6
// 322.141 us; speedup vs baseline: 2.3779x; 2.3779x over previous
//
#include <hip/hip_runtime.h>
#include <hip/hip_bf16.h>

// Problem constants
constexpr int kB  = 1024;
constexpr int kV  = 6890;
constexpr int kJ  = 24;
constexpr int kNB = 10;
constexpr int kP  = 207;   // 23*9
constexpr int kH  = 17;
constexpr int TB  = 8;     // batch tile in k_lbs

constexpr int kN   = kV * 3;      // 20670
constexpr int kKP  = 224;         // K padded: 207 pf + 10 betas + 7 zero
constexpr int kNT  = 1296;        // n-tiles of 16 (N_pad = 20736)
constexpr int kNP  = kNT * 16;    // 20736

// Output layout (flat concat, FP32 elements)
constexpr size_t O_VERTS  = 0;
constexpr size_t O_JOINTS = (size_t)kB * kV * 3;              // 21166080
constexpr size_t O_ROT    = O_JOINTS + (size_t)kB * kJ * 3;   // 21239808
constexpr size_t O_JFV    = O_ROT + (size_t)kB * kJ * 9;      // 21460992

// Workspace layout (fp32 elements)
constexpr size_t WS_JS   = 0;                        // 792 floats
constexpr size_t WS_FLAG = 1000;                     // 1 int
constexpr size_t WS_A    = 1024;                     // kB*288
constexpr size_t WS_PF   = WS_A + (size_t)kB * 288;  // kB*207
constexpr size_t WS_ROOT = WS_PF + (size_t)kB * kP;  // kB*3
constexpr size_t WS_JFV  = WS_ROOT + (size_t)kB * 3; // kB*51
constexpr size_t WS_ASWZ = 563200;                   // 1024*224 ushort = 114688 floats
constexpr size_t WS_BSWZ = WS_ASWZ + 114688;         // 1296*7*512 ushort = 2322432 floats

typedef __attribute__((ext_vector_type(8))) short short8;
typedef __attribute__((ext_vector_type(4))) float float4v;

__device__ __forceinline__ unsigned short f2bf(float f) {
    unsigned u = __float_as_uint(f);
    unsigned r = (u + 0x7FFFu + ((u >> 16) & 1u)) >> 16;  // RNE
    return (unsigned short)r;
}

// ---------------------------------------------------------------------------
// Classifier for the two 165360-element inputs (J_regressor vs lbs_weights).
// ---------------------------------------------------------------------------
__global__ void k_classify(const float* __restrict__ amb0, int* __restrict__ flag)
{
    if (blockIdx.x == 0 && threadIdx.x == 0) {
        float s = 0.f;
        for (int i = 0; i < kJ; i++) s += amb0[i];
        *flag = (fabsf(s - 1.0f) < 0.5f) ? 1 : 0;
    }
}

// ---------------------------------------------------------------------------
// Kernel 0: js[(j*3+k)*11 + l]: Jreg @ shapedirs (l<10) and Jreg @ v_template.
// ---------------------------------------------------------------------------
__global__ __launch_bounds__(256) void k_js(
    const float* __restrict__ amb0,
    const float* __restrict__ amb1,
    const int* __restrict__ flag,
    const float* __restrict__ sd,
    const float* __restrict__ vt,
    float* __restrict__ js)
{
    const float* Jreg = (*flag) ? amb1 : amb0;
    int j = blockIdx.x / 11;
    int l = blockIdx.x % 11;
    int t = threadIdx.x;
    float a0 = 0.f, a1 = 0.f, a2 = 0.f;
    for (int v = t; v < kV; v += 256) {
        float w = Jreg[j * kV + v];
        if (l < kNB) {
            a0 += w * sd[(v * 3 + 0) * kNB + l];
            a1 += w * sd[(v * 3 + 1) * kNB + l];
            a2 += w * sd[(v * 3 + 2) * kNB + l];
        } else {
            a0 += w * vt[v * 3 + 0];
            a1 += w * vt[v * 3 + 1];
            a2 += w * vt[v * 3 + 2];
        }
    }
    __shared__ float r0[256], r1[256], r2[256];
    r0[t] = a0; r1[t] = a1; r2[t] = a2;
    __syncthreads();
    for (int s = 128; s > 0; s >>= 1) {
        if (t < s) { r0[t] += r0[t + s]; r1[t] += r1[t + s]; r2[t] += r2[t + s]; }
        __syncthreads();
    }
    if (t == 0) {
        js[(j * 3 + 0) * 11 + l] = r0[0];
        js[(j * 3 + 1) * 11 + l] = r1[0];
        js[(j * 3 + 2) * 11 + l] = r2[0];
    }
}

// ---------------------------------------------------------------------------
// Kernel 1: per-batch rodrigues + FK chain + A matrices.
// ---------------------------------------------------------------------------
__global__ __launch_bounds__(64) void k_pose(
    const float* __restrict__ pose,
    const float* __restrict__ betas,
    const float* __restrict__ gor,
    const float* __restrict__ js,
    float* __restrict__ wsA,
    float* __restrict__ wsPF,
    float* __restrict__ wsRoot,
    float* __restrict__ out)
{
    __shared__ float Rsh[kJ][9];
    __shared__ float Jr[kJ][3];
    __shared__ float G[kJ][12];

    int b = blockIdx.x;
    int t = threadIdx.x;

    if (t < kJ) {
        float rx, ry, rz;
        if (t == 0) {
            rx = gor[b * 3 + 0]; ry = gor[b * 3 + 1]; rz = gor[b * 3 + 2];
        } else {
            int o = b * 69 + (t - 1) * 3;
            rx = pose[o]; ry = pose[o + 1]; rz = pose[o + 2];
        }
        float ex = rx + 1e-8f, ey = ry + 1e-8f, ez = rz + 1e-8f;
        float ang = sqrtf(ex * ex + ey * ey + ez * ez);
        float x = rx / ang, y = ry / ang, z = rz / ang;
        float s = sinf(ang), c = cosf(ang), oc = 1.0f - c;
        float r[9];
        r[0] = 1.0f - oc * (y * y + z * z);
        r[1] = -s * z + oc * (x * y);
        r[2] =  s * y + oc * (x * z);
        r[3] =  s * z + oc * (x * y);
        r[4] = 1.0f - oc * (x * x + z * z);
        r[5] = -s * x + oc * (y * z);
        r[6] = -s * y + oc * (x * z);
        r[7] =  s * x + oc * (y * z);
        r[8] = 1.0f - oc * (x * x + y * y);
        #pragma unroll
        for (int i = 0; i < 9; i++) Rsh[t][i] = r[i];
        float* ro = out + O_ROT + (size_t)b * (kJ * 9) + (size_t)t * 9;
        #pragma unroll
        for (int i = 0; i < 9; i++) ro[i] = r[i];
        if (t >= 1) {
            float* pf = wsPF + (size_t)b * kP + (size_t)(t - 1) * 9;
            #pragma unroll
            for (int i = 0; i < 9; i++)
                pf[i] = r[i] - ((i == 0 || i == 4 || i == 8) ? 1.0f : 0.0f);
        }
        float bt[kNB];
        #pragma unroll
        for (int l = 0; l < kNB; l++) bt[l] = betas[b * kNB + l];
        #pragma unroll
        for (int k = 0; k < 3; k++) {
            const float* row = js + (t * 3 + k) * 11;
            float acc = row[10];
            #pragma unroll
            for (int l = 0; l < kNB; l++) acc += bt[l] * row[l];
            Jr[t][k] = acc;
        }
    }
    __syncthreads();

    if (t == 0) {
        const int par[kJ] = {-1,0,0,0,1,2,3,4,5,6,7,8,9,9,9,12,13,14,16,17,18,19,20,21};
        #pragma unroll
        for (int m = 0; m < 3; m++) {
            #pragma unroll
            for (int n = 0; n < 3; n++) G[0][m * 4 + n] = Rsh[0][m * 3 + n];
            G[0][m * 4 + 3] = Jr[0][m];
        }
        for (int i = 1; i < kJ; i++) {
            int p = par[i];
            float rel[3];
            #pragma unroll
            for (int k = 0; k < 3; k++) rel[k] = Jr[i][k] - Jr[p][k];
            #pragma unroll
            for (int m = 0; m < 3; m++) {
                float g0 = G[p][m * 4 + 0], g1 = G[p][m * 4 + 1], g2 = G[p][m * 4 + 2];
                #pragma unroll
                for (int n = 0; n < 3; n++) {
                    G[i][m * 4 + n] = g0 * Rsh[i][0 * 3 + n]
                                    + g1 * Rsh[i][1 * 3 + n]
                                    + g2 * Rsh[i][2 * 3 + n];
                }
                G[i][m * 4 + 3] = g0 * rel[0] + g1 * rel[1] + g2 * rel[2]
                                + G[p][m * 4 + 3];
            }
        }
    }
    __syncthreads();

    if (t < kJ) {
        float* Aj = wsA + (size_t)b * 288 + (size_t)t * 12;
        float* jo = out + O_JOINTS + (size_t)b * (kJ * 3) + (size_t)t * 3;
        #pragma unroll
        for (int m = 0; m < 3; m++) {
            float g0 = G[t][m * 4 + 0], g1 = G[t][m * 4 + 1], g2 = G[t][m * 4 + 2];
            Aj[m * 4 + 0] = g0;
            Aj[m * 4 + 1] = g1;
            Aj[m * 4 + 2] = g2;
            Aj[m * 4 + 3] = G[t][m * 4 + 3]
                          - (g0 * Jr[t][0] + g1 * Jr[t][1] + g2 * Jr[t][2]);
            jo[m] = G[t][m * 4 + 3] - G[0][m * 4 + 3];
        }
        if (t == 0) {
            #pragma unroll
            for (int k = 0; k < 3; k++) wsRoot[b * 3 + k] = G[0][k * 4 + 3];
        }
    }
}

// ---------------------------------------------------------------------------
// k_prep_b: build swizzled bf16 B matrix (K_pad=224 x N_pad=20736).
//   rows 0..206 = posedirs, 207..216 = shapedirs^T (sd[n*10+l]), rest 0.
// Fragment-major layout per (ntile,ktile) 16x32 tile of 512 bf16:
//   addr = (ntile*7 + ktile)*512 + quad*128 + nin*8 + kin
// so a wave's B-fragment load is lane*16B contiguous.
// ---------------------------------------------------------------------------
__global__ __launch_bounds__(256) void k_prep_b(
    const float* __restrict__ pd,
    const float* __restrict__ sd,
    unsigned short* __restrict__ bswz)
{
    __shared__ unsigned short lds[kKP][68];  // 64 cols + pad
    int g = blockIdx.x;          // 64-column group, 0..323
    int n0 = g * 64;
    int t = threadIdx.x;

    // Phase 1: coalesced load + convert
    for (int kbase = 0; kbase < kKP; kbase += 4) {
        int k = kbase + (t >> 6);
        int nl = t & 63;
        int n = n0 + nl;
        float val = 0.f;
        if (n < kN) {
            if (k < kP)            val = pd[(size_t)k * kN + n];
            else if (k < kP + kNB) val = sd[(size_t)n * kNB + (k - kP)];
        }
        lds[k][nl] = f2bf(val);
    }
    __syncthreads();

    // Phase 2: write swizzled, coalesced
    #pragma unroll 1
    for (int tt = 0; tt < 4; tt++) {
        int ntile = g * 4 + tt;
        #pragma unroll 1
        for (int kt = 0; kt < 7; kt++) {
            size_t base = ((size_t)ntile * 7 + kt) * 512;
            #pragma unroll
            for (int u = 0; u < 2; u++) {
                int e = t * 2 + u;
                int quad = e >> 7, rem = e & 127;
                int nin = rem >> 3, kin = rem & 7;
                int k = kt * 32 + quad * 8 + kin;
                bswz[base + e] = lds[k][tt * 16 + nin];
            }
        }
    }
}

// ---------------------------------------------------------------------------
// k_prep_a: build swizzled bf16 A matrix (M=1024 x K_pad=224) from pf+betas.
//   addr = (mtile*7 + ktile)*512 + quad*128 + min*8 + kin
// ---------------------------------------------------------------------------
__global__ __launch_bounds__(256) void k_prep_a(
    const float* __restrict__ wsPF,
    const float* __restrict__ betas,
    unsigned short* __restrict__ aswz)
{
    int mtile = blockIdx.x;   // 0..63
    int t = threadIdx.x;
    for (int e = t; e < 16 * kKP; e += 256) {
        int kt = e >> 9, r = e & 511;
        int quad = r >> 7, min_ = (r >> 3) & 15, kin = r & 7;
        int k = kt * 32 + quad * 8 + kin;
        int b = mtile * 16 + min_;
        float val = 0.f;
        if (k < kP)            val = wsPF[(size_t)b * kP + k];
        else if (k < kP + kNB) val = betas[(size_t)b * kNB + (k - kP)];
        aswz[((size_t)mtile * 7 + kt) * 512 + r] = f2bf(val);
    }
}

// ---------------------------------------------------------------------------
// k_gemm: disp[b][n] = A(1024x224) @ B(224x20670), MFMA 16x16x32 bf16.
// Block = 128x128 (2x2 waves of 64x64). Direct swizzled global fragment loads.
// Writes fp32 displacement into out[O_VERTS] (overwritten in-place by k_lbs).
// ---------------------------------------------------------------------------
__global__ __launch_bounds__(256) void k_gemm(
    const unsigned short* __restrict__ A,
    const unsigned short* __restrict__ B,
    float* __restrict__ out)
{
    int tid = threadIdx.x;
    int lane = tid & 63;
    int wid = tid >> 6;
    int m0t = blockIdx.y * 8 + (wid >> 1) * 4;   // base m-tile (of 16)
    int n0t = blockIdx.x * 8 + (wid & 1) * 4;    // base n-tile (of 16)

    float4v acc[4][4];
    #pragma unroll
    for (int i = 0; i < 4; i++)
        #pragma unroll
        for (int j = 0; j < 4; j++)
            acc[i][j] = (float4v){0.f, 0.f, 0.f, 0.f};

    #pragma unroll
    for (int kt = 0; kt < 7; kt++) {
        short8 a[4], b[4];
        #pragma unroll
        for (int i = 0; i < 4; i++)
            a[i] = *(const short8*)(A + ((size_t)(m0t + i) * 7 + kt) * 512 + lane * 8);
        #pragma unroll
        for (int j = 0; j < 4; j++)
            b[j] = *(const short8*)(B + ((size_t)(n0t + j) * 7 + kt) * 512 + lane * 8);
        #pragma unroll
        for (int i = 0; i < 4; i++)
            #pragma unroll
            for (int j = 0; j < 4; j++)
                acc[i][j] = __builtin_amdgcn_mfma_f32_16x16x32_bf16(
                    a[i], b[j], acc[i][j], 0, 0, 0);
    }

    int rbase = (lane >> 4) * 4;
    int col = lane & 15;
    #pragma unroll
    for (int i = 0; i < 4; i++) {
        #pragma unroll
        for (int j = 0; j < 4; j++) {
            int n = (n0t + j) * 16 + col;
            if (n < kN) {
                #pragma unroll
                for (int reg = 0; reg < 4; reg++) {
                    int brow = (m0t + i) * 16 + rbase + reg;
                    out[O_VERTS + (size_t)brow * kN + n] = acc[i][j][reg];
                }
            }
        }
    }
}

// ---------------------------------------------------------------------------
// k_lbs: verts = Tv_rot @ (vt + disp) + Tv_t - root, disp read in-place from out.
// ---------------------------------------------------------------------------
__global__ __launch_bounds__(256) void k_lbs(
    const float* __restrict__ vt,
    const float* __restrict__ amb0,
    const float* __restrict__ amb1,
    const int* __restrict__ flag,
    const float* __restrict__ wsA,
    const float* __restrict__ wsRoot,
    float* __restrict__ out)
{
    __shared__ float sA[TB][288];
    __shared__ float sRoot[TB][3];

    const float* W = (*flag) ? amb0 : amb1;   // lbs_weights (V,24)

    int t = threadIdx.x;
    int b0 = blockIdx.y * TB;

    for (int i = t; i < TB * 288; i += 256)
        sA[i / 288][i % 288] = wsA[(size_t)(b0 + i / 288) * 288 + (i % 288)];
    if (t < TB * 3)
        sRoot[t / 3][t % 3] = wsRoot[(size_t)(b0 + t / 3) * 3 + (t % 3)];
    __syncthreads();

    int v = blockIdx.x * 256 + t;
    if (v >= kV) return;

    float t0 = vt[v * 3 + 0], t1 = vt[v * 3 + 1], t2 = vt[v * 3 + 2];
    float w[kJ];
    {
        const float* Wv = W + (size_t)v * kJ;
        #pragma unroll
        for (int j = 0; j < kJ; j++) w[j] = Wv[j];
    }
    #pragma unroll 1
    for (int tb = 0; tb < TB; tb++) {
        float Tv[12];
        #pragma unroll
        for (int i = 0; i < 12; i++) Tv[i] = 0.f;
        #pragma unroll
        for (int j = 0; j < kJ; j++) {
            float wj = w[j];
            #pragma unroll
            for (int i = 0; i < 12; i++) Tv[i] += wj * sA[tb][j * 12 + i];
        }
        float* op = out + O_VERTS + ((size_t)(b0 + tb) * kV + v) * 3;
        float x = t0 + op[0];
        float y = t1 + op[1];
        float z = t2 + op[2];
        float o0 = Tv[0] * x + Tv[1] * y + Tv[2]  * z + Tv[3]  - sRoot[tb][0];
        float o1 = Tv[4] * x + Tv[5] * y + Tv[6]  * z + Tv[7]  - sRoot[tb][1];
        float o2 = Tv[8] * x + Tv[9] * y + Tv[10] * z + Tv[11] - sRoot[tb][2];
        op[0] = o0;
        op[1] = o1;
        op[2] = o2;
    }
}

// ---------------------------------------------------------------------------
// k_jfv: jfv[b,j,k] = sum_v Jh[j,v] * verts_out[b,v,k]
// ---------------------------------------------------------------------------
__global__ __launch_bounds__(256) void k_jfv(
    const float* __restrict__ Jh,
    const float* __restrict__ vertsOut,
    float* __restrict__ wsJfv)
{
    int b = blockIdx.x;
    int t = threadIdx.x;
    int lane = t & 63;
    int wave = t >> 6;

    float acc[kH * 3];
    #pragma unroll
    for (int i = 0; i < kH * 3; i++) acc[i] = 0.f;

    for (int v = t; v < kV; v += 256) {
        const float* vpt = vertsOut + ((size_t)b * kV + v) * 3;
        float vx = vpt[0], vy = vpt[1], vz = vpt[2];
        #pragma unroll
        for (int j = 0; j < kH; j++) {
            float wj = Jh[(size_t)j * kV + v];
            acc[j * 3 + 0] += wj * vx;
            acc[j * 3 + 1] += wj * vy;
            acc[j * 3 + 2] += wj * vz;
        }
    }
    #pragma unroll
    for (int off = 32; off > 0; off >>= 1) {
        #pragma unroll
        for (int i = 0; i < kH * 3; i++)
            acc[i] += __shfl_down(acc[i], off, 64);
    }
    __shared__ float partial[4][kH * 3];
    if (lane == 0) {
        #pragma unroll
        for (int i = 0; i < kH * 3; i++) partial[wave][i] = acc[i];
    }
    __syncthreads();
    if (t < kH * 3) {
        float s = partial[0][t] + partial[1][t] + partial[2][t] + partial[3][t];
        wsJfv[(size_t)b * 51 + t] = s;
    }
}

__global__ __launch_bounds__(64) void k_jfv_out(
    const float* __restrict__ wsJfv,
    float* __restrict__ out)
{
    int b = blockIdx.x;
    int t = threadIdx.x;
    if (t < kH * 3) {
        int k = t % 3;
        float val = wsJfv[(size_t)b * 51 + t] - wsJfv[(size_t)b * 51 + k];
        out[O_JFV + (size_t)b * 51 + t] = val;
    }
}

extern "C" void kernel_launch(void* const* d_in, const int* in_sizes, int n_in,
                              void* d_out, int out_size, void* d_ws, size_t ws_size,
                              hipStream_t stream) {
    const float *pose = nullptr, *betas = nullptr, *gor = nullptr, *vt = nullptr,
                *sd = nullptr, *pd = nullptr, *Jh = nullptr;
    const float *amb0 = nullptr, *amb1 = nullptr;
    for (int i = 0; i < n_in; i++) {
        const float* p = (const float*)d_in[i];
        switch (in_sizes[i]) {
            case 70656:   pose  = p; break;
            case 10240:   betas = p; break;
            case 3072:    gor   = p; break;
            case 20670:   vt    = p; break;
            case 206700:  sd    = p; break;
            case 4278690: pd    = p; break;
            case 117130:  Jh    = p; break;
            case 165360:  if (!amb0) amb0 = p; else amb1 = p; break;
            default: break;
        }
    }

    float* ws = (float*)d_ws;
    float* js     = ws + WS_JS;
    int*   flag   = (int*)(ws + WS_FLAG);
    float* wsA    = ws + WS_A;
    float* wsPF   = ws + WS_PF;
    float* wsRoot = ws + WS_ROOT;
    float* wsJfv  = ws + WS_JFV;
    unsigned short* aswz = (unsigned short*)(ws + WS_ASWZ);
    unsigned short* bswz = (unsigned short*)(ws + WS_BSWZ);

    float* out = (float*)d_out;

    k_classify<<<dim3(1), dim3(64), 0, stream>>>(amb0, flag);
    k_js<<<dim3(kJ * 11), dim3(256), 0, stream>>>(amb0, amb1, flag, sd, vt, js);
    k_pose<<<dim3(kB), dim3(64), 0, stream>>>(pose, betas, gor, js, wsA, wsPF, wsRoot, out);
    k_prep_b<<<dim3(kNP / 64), dim3(256), 0, stream>>>(pd, sd, bswz);
    k_prep_a<<<dim3(64), dim3(256), 0, stream>>>(wsPF, betas, aswz);
    k_gemm<<<dim3(kNT / 8, kB / 128), dim3(256), 0, stream>>>(aswz, bswz, out);
    k_lbs<<<dim3((kV + 255) / 256, kB / TB), dim3(256), 0, stream>>>(
        vt, amb0, amb1, flag, wsA, wsRoot, out);
    k_jfv<<<dim3(kB), dim3(256), 0, stream>>>(Jh, out + O_VERTS, wsJfv);
    k_jfv_out<<<dim3(kB), dim3(64), 0, stream>>>(wsJfv, out);
}

// Round 7
// 306.402 us; speedup vs baseline: 2.5000x; 1.0514x over previous
//
#include <hip/hip_runtime.h>
#include <hip/hip_bf16.h>

// Problem constants
constexpr int kB  = 1024;
constexpr int kV  = 6890;
constexpr int kJ  = 24;
constexpr int kNB = 10;
constexpr int kP  = 207;   // 23*9
constexpr int kH  = 17;
constexpr int TB  = 8;     // batch tile in k_lbs

constexpr int kN   = kV * 3;      // 20670
constexpr int kKP  = 224;         // K padded: 207 pf + 10 betas + 1 vt + 6 zero
constexpr int kNT  = 1296;        // n-tiles of 16 (N_pad = 20736)
constexpr int kNP  = kNT * 16;    // 20736
constexpr int kVC  = 862;         // v-chunk for k_js (8 chunks)

// Output layout (flat concat, FP32 elements)
constexpr size_t O_VERTS  = 0;
constexpr size_t O_JOINTS = (size_t)kB * kV * 3;              // 21166080
constexpr size_t O_ROT    = O_JOINTS + (size_t)kB * kJ * 3;   // 21239808
constexpr size_t O_JFV    = O_ROT + (size_t)kB * kJ * 9;      // 21460992

// Workspace layout (fp32 elements)
constexpr size_t WS_JS   = 0;                        // 792 floats
constexpr size_t WS_FLAG = 1000;                     // 1 int
constexpr size_t WS_A    = 1024;                     // kB*288
constexpr size_t WS_PF   = WS_A + (size_t)kB * 288;  // kB*207
constexpr size_t WS_ROOT = WS_PF + (size_t)kB * kP;  // kB*3
constexpr size_t WS_JFV  = WS_ROOT + (size_t)kB * 3; // kB*51
constexpr size_t WS_ASWZ = 563200;                   // 1024*224 ushort = 114688 floats
constexpr size_t WS_BSWZ = WS_ASWZ + 114688;         // 1296*7*512 ushort = 2322432 floats
// overlays (dead-region reuse):
//   js partials: WS_ASWZ region (used k_js -> k_js_reduce, before k_prep_a)
//   JhT:         WS_BSWZ region (used k_prep_jh -> k_jfv, after k_gemm)

typedef __attribute__((ext_vector_type(8))) short short8;
typedef __attribute__((ext_vector_type(4))) float float4v;

__device__ __forceinline__ unsigned short f2bf(float f) {
    unsigned u = __float_as_uint(f);
    unsigned r = (u + 0x7FFFu + ((u >> 16) & 1u)) >> 16;  // RNE
    return (unsigned short)r;
}

// ---------------------------------------------------------------------------
// Classifier for the two 165360-element inputs (J_regressor vs lbs_weights).
// ---------------------------------------------------------------------------
__global__ void k_classify(const float* __restrict__ amb0, int* __restrict__ flag)
{
    if (blockIdx.x == 0 && threadIdx.x == 0) {
        float s = 0.f;
        for (int i = 0; i < kJ; i++) s += amb0[i];
        *flag = (fabsf(s - 1.0f) < 0.5f) ? 1 : 0;
    }
}

// ---------------------------------------------------------------------------
// k_js: partial[(j*8+c)*33 + i] = sum over v-chunk c of Jreg[j,v]*[sd|vt].
// Coalesced: each thread reads sd[v*30..+29] (dwordx4) + vt[v*3..+2].
// acc index i = k*11 + l (l<10: sd, l==10: vt).
// ---------------------------------------------------------------------------
__global__ __launch_bounds__(256) void k_js(
    const float* __restrict__ amb0,
    const float* __restrict__ amb1,
    const int* __restrict__ flag,
    const float* __restrict__ sd,
    const float* __restrict__ vt,
    float* __restrict__ partial)
{
    const float* Jreg = (*flag) ? amb1 : amb0;
    int j = blockIdx.x;
    int c = blockIdx.y;
    int t = threadIdx.x;
    int lane = t & 63;
    int wave = t >> 6;

    float acc[33];
    #pragma unroll
    for (int i = 0; i < 33; i++) acc[i] = 0.f;

    int vend = min(kVC * (c + 1), kV);
    for (int v = kVC * c + t; v < vend; v += 256) {
        float w = Jreg[j * kV + v];
        const float* sdp = sd + (size_t)v * 30;
        #pragma unroll
        for (int k = 0; k < 3; k++) {
            #pragma unroll
            for (int l = 0; l < kNB; l++)
                acc[k * 11 + l] += w * sdp[k * 10 + l];
            acc[k * 11 + 10] += w * vt[v * 3 + k];
        }
    }
    #pragma unroll
    for (int off = 32; off > 0; off >>= 1) {
        #pragma unroll
        for (int i = 0; i < 33; i++)
            acc[i] += __shfl_down(acc[i], off, 64);
    }
    __shared__ float red[4][33];
    if (lane == 0) {
        #pragma unroll
        for (int i = 0; i < 33; i++) red[wave][i] = acc[i];
    }
    __syncthreads();
    if (t < 33) {
        float s = red[0][t] + red[1][t] + red[2][t] + red[3][t];
        partial[((size_t)j * 8 + c) * 33 + t] = s;
    }
}

__global__ __launch_bounds__(1024) void k_js_reduce(
    const float* __restrict__ partial,
    float* __restrict__ js)
{
    int t = threadIdx.x;
    if (t < 24 * 33) {
        int j = t / 33, i = t % 33;
        float s = 0.f;
        #pragma unroll
        for (int c = 0; c < 8; c++) s += partial[((size_t)j * 8 + c) * 33 + i];
        js[t] = s;   // js[j*33 + k*11 + l] == js[(j*3+k)*11 + l]
    }
}

// ---------------------------------------------------------------------------
// Kernel 1: per-batch rodrigues + FK chain + A matrices.
// ---------------------------------------------------------------------------
__global__ __launch_bounds__(64) void k_pose(
    const float* __restrict__ pose,
    const float* __restrict__ betas,
    const float* __restrict__ gor,
    const float* __restrict__ js,
    float* __restrict__ wsA,
    float* __restrict__ wsPF,
    float* __restrict__ wsRoot,
    float* __restrict__ out)
{
    __shared__ float Rsh[kJ][9];
    __shared__ float Jr[kJ][3];
    __shared__ float G[kJ][12];

    int b = blockIdx.x;
    int t = threadIdx.x;

    if (t < kJ) {
        float rx, ry, rz;
        if (t == 0) {
            rx = gor[b * 3 + 0]; ry = gor[b * 3 + 1]; rz = gor[b * 3 + 2];
        } else {
            int o = b * 69 + (t - 1) * 3;
            rx = pose[o]; ry = pose[o + 1]; rz = pose[o + 2];
        }
        float ex = rx + 1e-8f, ey = ry + 1e-8f, ez = rz + 1e-8f;
        float ang = sqrtf(ex * ex + ey * ey + ez * ez);
        float x = rx / ang, y = ry / ang, z = rz / ang;
        float s = sinf(ang), c = cosf(ang), oc = 1.0f - c;
        float r[9];
        r[0] = 1.0f - oc * (y * y + z * z);
        r[1] = -s * z + oc * (x * y);
        r[2] =  s * y + oc * (x * z);
        r[3] =  s * z + oc * (x * y);
        r[4] = 1.0f - oc * (x * x + z * z);
        r[5] = -s * x + oc * (y * z);
        r[6] = -s * y + oc * (x * z);
        r[7] =  s * x + oc * (y * z);
        r[8] = 1.0f - oc * (x * x + y * y);
        #pragma unroll
        for (int i = 0; i < 9; i++) Rsh[t][i] = r[i];
        float* ro = out + O_ROT + (size_t)b * (kJ * 9) + (size_t)t * 9;
        #pragma unroll
        for (int i = 0; i < 9; i++) ro[i] = r[i];
        if (t >= 1) {
            float* pf = wsPF + (size_t)b * kP + (size_t)(t - 1) * 9;
            #pragma unroll
            for (int i = 0; i < 9; i++)
                pf[i] = r[i] - ((i == 0 || i == 4 || i == 8) ? 1.0f : 0.0f);
        }
        float bt[kNB];
        #pragma unroll
        for (int l = 0; l < kNB; l++) bt[l] = betas[b * kNB + l];
        #pragma unroll
        for (int k = 0; k < 3; k++) {
            const float* row = js + (t * 3 + k) * 11;
            float acc = row[10];
            #pragma unroll
            for (int l = 0; l < kNB; l++) acc += bt[l] * row[l];
            Jr[t][k] = acc;
        }
    }
    __syncthreads();

    if (t == 0) {
        const int par[kJ] = {-1,0,0,0,1,2,3,4,5,6,7,8,9,9,9,12,13,14,16,17,18,19,20,21};
        #pragma unroll
        for (int m = 0; m < 3; m++) {
            #pragma unroll
            for (int n = 0; n < 3; n++) G[0][m * 4 + n] = Rsh[0][m * 3 + n];
            G[0][m * 4 + 3] = Jr[0][m];
        }
        for (int i = 1; i < kJ; i++) {
            int p = par[i];
            float rel[3];
            #pragma unroll
            for (int k = 0; k < 3; k++) rel[k] = Jr[i][k] - Jr[p][k];
            #pragma unroll
            for (int m = 0; m < 3; m++) {
                float g0 = G[p][m * 4 + 0], g1 = G[p][m * 4 + 1], g2 = G[p][m * 4 + 2];
                #pragma unroll
                for (int n = 0; n < 3; n++) {
                    G[i][m * 4 + n] = g0 * Rsh[i][0 * 3 + n]
                                    + g1 * Rsh[i][1 * 3 + n]
                                    + g2 * Rsh[i][2 * 3 + n];
                }
                G[i][m * 4 + 3] = g0 * rel[0] + g1 * rel[1] + g2 * rel[2]
                                + G[p][m * 4 + 3];
            }
        }
    }
    __syncthreads();

    if (t < kJ) {
        float* Aj = wsA + (size_t)b * 288 + (size_t)t * 12;
        float* jo = out + O_JOINTS + (size_t)b * (kJ * 3) + (size_t)t * 3;
        #pragma unroll
        for (int m = 0; m < 3; m++) {
            float g0 = G[t][m * 4 + 0], g1 = G[t][m * 4 + 1], g2 = G[t][m * 4 + 2];
            Aj[m * 4 + 0] = g0;
            Aj[m * 4 + 1] = g1;
            Aj[m * 4 + 2] = g2;
            Aj[m * 4 + 3] = G[t][m * 4 + 3]
                          - (g0 * Jr[t][0] + g1 * Jr[t][1] + g2 * Jr[t][2]);
            jo[m] = G[t][m * 4 + 3] - G[0][m * 4 + 3];
        }
        if (t == 0) {
            #pragma unroll
            for (int k = 0; k < 3; k++) wsRoot[b * 3 + k] = G[0][k * 4 + 3];
        }
    }
}

// ---------------------------------------------------------------------------
// k_prep_b: swizzled bf16 B (K_pad=224 x N_pad=20736).
//   rows 0..206 = posedirs, 207..216 = shapedirs^T, 217 = v_template, rest 0.
// ---------------------------------------------------------------------------
__global__ __launch_bounds__(256) void k_prep_b(
    const float* __restrict__ pd,
    const float* __restrict__ sd,
    const float* __restrict__ vt,
    unsigned short* __restrict__ bswz)
{
    __shared__ unsigned short lds[kKP][68];
    int g = blockIdx.x;
    int n0 = g * 64;
    int t = threadIdx.x;

    for (int kbase = 0; kbase < kKP; kbase += 4) {
        int k = kbase + (t >> 6);
        int nl = t & 63;
        int n = n0 + nl;
        float val = 0.f;
        if (n < kN) {
            if (k < kP)                 val = pd[(size_t)k * kN + n];
            else if (k < kP + kNB)      val = sd[(size_t)n * kNB + (k - kP)];
            else if (k == kP + kNB)     val = vt[n];
        }
        lds[k][nl] = f2bf(val);
    }
    __syncthreads();

    #pragma unroll 1
    for (int tt = 0; tt < 4; tt++) {
        int ntile = g * 4 + tt;
        #pragma unroll 1
        for (int kt = 0; kt < 7; kt++) {
            size_t base = ((size_t)ntile * 7 + kt) * 512;
            #pragma unroll
            for (int u = 0; u < 2; u++) {
                int e = t * 2 + u;
                int quad = e >> 7, rem = e & 127;
                int nin = rem >> 3, kin = rem & 7;
                int k = kt * 32 + quad * 8 + kin;
                bswz[base + e] = lds[k][tt * 16 + nin];
            }
        }
    }
}

// ---------------------------------------------------------------------------
// k_prep_a: swizzled bf16 A (M=1024 x K_pad=224): pf | betas | 1.0 | 0.
// ---------------------------------------------------------------------------
__global__ __launch_bounds__(256) void k_prep_a(
    const float* __restrict__ wsPF,
    const float* __restrict__ betas,
    unsigned short* __restrict__ aswz)
{
    int mtile = blockIdx.x;   // 0..63
    int t = threadIdx.x;
    for (int e = t; e < 16 * kKP; e += 256) {
        int kt = e >> 9, r = e & 511;
        int quad = r >> 7, min_ = (r >> 3) & 15, kin = r & 7;
        int k = kt * 32 + quad * 8 + kin;
        int b = mtile * 16 + min_;
        float val = 0.f;
        if (k < kP)             val = wsPF[(size_t)b * kP + k];
        else if (k < kP + kNB)  val = betas[(size_t)b * kNB + (k - kP)];
        else if (k == kP + kNB) val = 1.0f;
        aswz[((size_t)mtile * 7 + kt) * 512 + r] = f2bf(val);
    }
}

// ---------------------------------------------------------------------------
// k_gemm: v_posed[b][n] = A(1024x224) @ B(224x20670) -> out[O_VERTS] (fp32).
// ---------------------------------------------------------------------------
__global__ __launch_bounds__(256) void k_gemm(
    const unsigned short* __restrict__ A,
    const unsigned short* __restrict__ B,
    float* __restrict__ out)
{
    int tid = threadIdx.x;
    int lane = tid & 63;
    int wid = tid >> 6;
    int m0t = blockIdx.y * 8 + (wid >> 1) * 4;
    int n0t = blockIdx.x * 8 + (wid & 1) * 4;

    float4v acc[4][4];
    #pragma unroll
    for (int i = 0; i < 4; i++)
        #pragma unroll
        for (int j = 0; j < 4; j++)
            acc[i][j] = (float4v){0.f, 0.f, 0.f, 0.f};

    #pragma unroll
    for (int kt = 0; kt < 7; kt++) {
        short8 a[4], b[4];
        #pragma unroll
        for (int i = 0; i < 4; i++)
            a[i] = *(const short8*)(A + ((size_t)(m0t + i) * 7 + kt) * 512 + lane * 8);
        #pragma unroll
        for (int j = 0; j < 4; j++)
            b[j] = *(const short8*)(B + ((size_t)(n0t + j) * 7 + kt) * 512 + lane * 8);
        #pragma unroll
        for (int i = 0; i < 4; i++)
            #pragma unroll
            for (int j = 0; j < 4; j++)
                acc[i][j] = __builtin_amdgcn_mfma_f32_16x16x32_bf16(
                    a[i], b[j], acc[i][j], 0, 0, 0);
    }

    int rbase = (lane >> 4) * 4;
    int col = lane & 15;
    #pragma unroll
    for (int i = 0; i < 4; i++) {
        #pragma unroll
        for (int j = 0; j < 4; j++) {
            int n = (n0t + j) * 16 + col;
            if (n < kN) {
                #pragma unroll
                for (int reg = 0; reg < 4; reg++) {
                    int brow = (m0t + i) * 16 + rbase + reg;
                    out[O_VERTS + (size_t)brow * kN + n] = acc[i][j][reg];
                }
            }
        }
    }
}

// ---------------------------------------------------------------------------
// k_prep_jh: JhT[v*17 + j] = Jh[j*kV + v]
// ---------------------------------------------------------------------------
__global__ __launch_bounds__(256) void k_prep_jh(
    const float* __restrict__ Jh,
    float* __restrict__ jht)
{
    int v = blockIdx.x * 256 + threadIdx.x;
    if (v >= kV) return;
    #pragma unroll
    for (int j = 0; j < kH; j++)
        jht[(size_t)v * kH + j] = Jh[(size_t)j * kV + v];
}

// ---------------------------------------------------------------------------
// k_lbs: verts = Tv_rot @ v_posed + Tv_t - root, v_posed read in-place.
// wsA/wsRoot accessed with wave-uniform indices -> SGPR (s_load) operands;
// no LDS at all.
// ---------------------------------------------------------------------------
__global__ __launch_bounds__(256) void k_lbs(
    const float* __restrict__ amb0,
    const float* __restrict__ amb1,
    const int* __restrict__ flag,
    const float* __restrict__ wsA,
    const float* __restrict__ wsRoot,
    float* __restrict__ out)
{
    const float* W = (*flag) ? amb0 : amb1;   // lbs_weights (V,24)

    int t = threadIdx.x;
    int b0 = blockIdx.y * TB;

    int v = blockIdx.x * 256 + t;
    if (v >= kV) return;

    float w[kJ];
    {
        const float* Wv = W + (size_t)v * kJ;
        #pragma unroll
        for (int j = 0; j < kJ; j++) w[j] = Wv[j];
    }
    #pragma unroll 1
    for (int tb = 0; tb < TB; tb++) {
        const float* Ab = wsA + (size_t)(b0 + tb) * 288;   // uniform -> SGPR
        float Tv[12];
        #pragma unroll
        for (int i = 0; i < 12; i++) Tv[i] = w[0] * Ab[i];
        #pragma unroll
        for (int j = 1; j < kJ; j++) {
            float wj = w[j];
            #pragma unroll
            for (int i = 0; i < 12; i++) Tv[i] += wj * Ab[j * 12 + i];
        }
        float r0 = wsRoot[(size_t)(b0 + tb) * 3 + 0];      // uniform -> SGPR
        float r1 = wsRoot[(size_t)(b0 + tb) * 3 + 1];
        float r2 = wsRoot[(size_t)(b0 + tb) * 3 + 2];
        float* op = out + O_VERTS + ((size_t)(b0 + tb) * kV + v) * 3;
        float x = op[0], y = op[1], z = op[2];
        float o0 = Tv[0] * x + Tv[1] * y + Tv[2]  * z + Tv[3]  - r0;
        float o1 = Tv[4] * x + Tv[5] * y + Tv[6]  * z + Tv[7]  - r1;
        float o2 = Tv[8] * x + Tv[9] * y + Tv[10] * z + Tv[11] - r2;
        op[0] = o0;
        op[1] = o1;
        op[2] = o2;
    }
}

// ---------------------------------------------------------------------------
// k_jfv: jfv[b,j,k] = sum_v JhT[v,j] * verts_out[b,v,k]
// ---------------------------------------------------------------------------
__global__ __launch_bounds__(256) void k_jfv(
    const float* __restrict__ jht,
    const float* __restrict__ vertsOut,
    float* __restrict__ wsJfv)
{
    int b = blockIdx.x;
    int t = threadIdx.x;
    int lane = t & 63;
    int wave = t >> 6;

    float acc[kH * 3];
    #pragma unroll
    for (int i = 0; i < kH * 3; i++) acc[i] = 0.f;

    for (int v = t; v < kV; v += 256) {
        const float* vpt = vertsOut + ((size_t)b * kV + v) * 3;
        float vx = vpt[0], vy = vpt[1], vz = vpt[2];
        const float* jt = jht + (size_t)v * kH;
        #pragma unroll
        for (int j = 0; j < kH; j++) {
            float wj = jt[j];
            acc[j * 3 + 0] += wj * vx;
            acc[j * 3 + 1] += wj * vy;
            acc[j * 3 + 2] += wj * vz;
        }
    }
    #pragma unroll
    for (int off = 32; off > 0; off >>= 1) {
        #pragma unroll
        for (int i = 0; i < kH * 3; i++)
            acc[i] += __shfl_down(acc[i], off, 64);
    }
    __shared__ float partial[4][kH * 3];
    if (lane == 0) {
        #pragma unroll
        for (int i = 0; i < kH * 3; i++) partial[wave][i] = acc[i];
    }
    __syncthreads();
    if (t < kH * 3) {
        float s = partial[0][t] + partial[1][t] + partial[2][t] + partial[3][t];
        wsJfv[(size_t)b * 51 + t] = s;
    }
}

__global__ __launch_bounds__(64) void k_jfv_out(
    const float* __restrict__ wsJfv,
    float* __restrict__ out)
{
    int b = blockIdx.x;
    int t = threadIdx.x;
    if (t < kH * 3) {
        int k = t % 3;
        float val = wsJfv[(size_t)b * 51 + t] - wsJfv[(size_t)b * 51 + k];
        out[O_JFV + (size_t)b * 51 + t] = val;
    }
}

extern "C" void kernel_launch(void* const* d_in, const int* in_sizes, int n_in,
                              void* d_out, int out_size, void* d_ws, size_t ws_size,
                              hipStream_t stream) {
    const float *pose = nullptr, *betas = nullptr, *gor = nullptr, *vt = nullptr,
                *sd = nullptr, *pd = nullptr, *Jh = nullptr;
    const float *amb0 = nullptr, *amb1 = nullptr;
    for (int i = 0; i < n_in; i++) {
        const float* p = (const float*)d_in[i];
        switch (in_sizes[i]) {
            case 70656:   pose  = p; break;
            case 10240:   betas = p; break;
            case 3072:    gor   = p; break;
            case 20670:   vt    = p; break;
            case 206700:  sd    = p; break;
            case 4278690: pd    = p; break;
            case 117130:  Jh    = p; break;
            case 165360:  if (!amb0) amb0 = p; else amb1 = p; break;
            default: break;
        }
    }

    float* ws = (float*)d_ws;
    float* js      = ws + WS_JS;
    int*   flag    = (int*)(ws + WS_FLAG);
    float* wsA     = ws + WS_A;
    float* wsPF    = ws + WS_PF;
    float* wsRoot  = ws + WS_ROOT;
    float* wsJfv   = ws + WS_JFV;
    unsigned short* aswz = (unsigned short*)(ws + WS_ASWZ);
    unsigned short* bswz = (unsigned short*)(ws + WS_BSWZ);
    float* jspart  = ws + WS_ASWZ;   // overlay: dead before k_prep_a
    float* jht     = ws + WS_BSWZ;   // overlay: dead after k_gemm

    float* out = (float*)d_out;

    k_classify<<<dim3(1), dim3(64), 0, stream>>>(amb0, flag);
    k_js<<<dim3(kJ, 8), dim3(256), 0, stream>>>(amb0, amb1, flag, sd, vt, jspart);
    k_js_reduce<<<dim3(1), dim3(1024), 0, stream>>>(jspart, js);
    k_pose<<<dim3(kB), dim3(64), 0, stream>>>(pose, betas, gor, js, wsA, wsPF, wsRoot, out);
    k_prep_b<<<dim3(kNP / 64), dim3(256), 0, stream>>>(pd, sd, vt, bswz);
    k_prep_a<<<dim3(64), dim3(256), 0, stream>>>(wsPF, betas, aswz);
    k_gemm<<<dim3(kNT / 8, kB / 128), dim3(256), 0, stream>>>(aswz, bswz, out);
    k_prep_jh<<<dim3((kV + 255) / 256), dim3(256), 0, stream>>>(Jh, jht);
    k_lbs<<<dim3((kV + 255) / 256, kB / TB), dim3(256), 0, stream>>>(
        amb0, amb1, flag, wsA, wsRoot, out);
    k_jfv<<<dim3(kB), dim3(256), 0, stream>>>(jht, out + O_VERTS, wsJfv);
    k_jfv_out<<<dim3(kB), dim3(64), 0, stream>>>(wsJfv, out);
}